// Round 6
// baseline (215.929 us; speedup 1.0000x reference)
//
#include <hip/hip_runtime.h>
#include <math.h>

typedef __attribute__((ext_vector_type(8))) short bf16x8;
typedef __attribute__((ext_vector_type(4))) float f32x4;

__device__ __forceinline__ ushort f2bf(float f) {
  union { float f; unsigned u; } v; v.f = f;
  return (ushort)((v.u + 0x8000u) >> 16);
}

// async global->LDS, 16B per lane. lds base wave-uniform; lane i lands at base + i*16B.
__device__ __forceinline__ void g2l16(const void* g, void* l) {
  __builtin_amdgcn_global_load_lds((const __attribute__((address_space(1))) unsigned*)g,
                                   (__attribute__((address_space(3))) unsigned*)l, 16, 0, 0);
}

// ---------------- merged cast kernel ----------------
// blocks [0,4096): x -> xbf.  blocks [4096,8192): Wq|Wk|Wv|Wo -> wcat.
// Wq gets 0.125*log2e folded in (softmax uses exp2).
__global__ __launch_bounds__(256) void cast_all(const float* __restrict__ x,
                                                const float* __restrict__ Wq,
                                                const float* __restrict__ Wk,
                                                const float* __restrict__ Wv,
                                                const float* __restrict__ Wo,
                                                ushort* __restrict__ xbf,
                                                ushort* __restrict__ wcat) {
  int i = blockIdx.x * 256 + threadIdx.x;
  if (i < 1048576) {
    float4 v = ((const float4*)x)[i];
    ushort4 u; u.x = f2bf(v.x); u.y = f2bf(v.y); u.z = f2bf(v.z); u.w = f2bf(v.w);
    ((ushort4*)xbf)[i] = u;
  } else {
    int j = i - 1048576;
    int sel = j >> 18;
    const float* src = (sel == 0) ? Wq : (sel == 1) ? Wk : (sel == 2) ? Wv : Wo;
    float scale = (sel == 0) ? 0.125f * 1.44269504088896f : 1.0f;
    float4 v = ((const float4*)src)[j & 0x3FFFF];
    ushort4 u;
    u.x = f2bf(v.x * scale); u.y = f2bf(v.y * scale);
    u.z = f2bf(v.z * scale); u.w = f2bf(v.w * scale);
    ((ushort4*)wcat)[j] = u;
  }
}

// ---------------- QKV GEMM: [4096][3072] = xbf @ Wqkv^T, V written transposed ----------------
// 128x128 tile, BK=32, dbuf global_load_lds. Q/K planes token-major; V plane written
// directly as Vt[bh=32][d=64][t=2048] (transpose fused into epilogue; sel is block-uniform).
__global__ __launch_bounds__(256) void gemm_qkv(const ushort* __restrict__ A,
                                                const ushort* __restrict__ B,
                                                ushort* __restrict__ QK,   // 2 planes of 4M
                                                ushort* __restrict__ Vt) {
  const int K = 1024;
  __shared__ __align__(16) ushort As[2][128 * 32];
  __shared__ __align__(16) ushort Bs[2][128 * 32];
  const int m0 = blockIdx.y * 128, n0 = blockIdx.x * 128;
  const int tid = threadIdx.x, lane = tid & 63, wid = tid >> 6;
  const int quad = lane >> 4, lc = lane & 15;
  const int lrow = lane >> 2, lcol = (lane & 3) * 8;
  const int wm = (wid >> 1) * 64, wn = (wid & 1) * 64;

  f32x4 acc[4][4] = {};

  auto stage = [&](int k0, int nb) {
    const ushort* Ag = A + (size_t)(m0 + wid * 32 + lrow) * K + k0 + lcol;
    g2l16(Ag, &As[nb][wid * 1024]);
    g2l16(Ag + (size_t)16 * K, &As[nb][wid * 1024 + 512]);
    const ushort* Bg = B + (size_t)(n0 + wid * 32 + lrow) * K + k0 + lcol;
    g2l16(Bg, &Bs[nb][wid * 1024]);
    g2l16(Bg + (size_t)16 * K, &Bs[nb][wid * 1024 + 512]);
  };

  stage(0, 0);
  for (int k0 = 0; k0 < K; k0 += 32) {
    const int nb = (k0 >> 5) & 1;
    __syncthreads();
    if (k0 + 32 < K) stage(k0 + 32, nb ^ 1);

    bf16x8 af[4], bfr[4];
#pragma unroll
    for (int t = 0; t < 4; t++)
      af[t] = *(const bf16x8*)&As[nb][(wm + t * 16 + lc) * 32 + quad * 8];
#pragma unroll
    for (int t = 0; t < 4; t++)
      bfr[t] = *(const bf16x8*)&Bs[nb][(wn + t * 16 + lc) * 32 + quad * 8];
#pragma unroll
    for (int mt = 0; mt < 4; mt++)
#pragma unroll
      for (int nt = 0; nt < 4; nt++)
        acc[mt][nt] = __builtin_amdgcn_mfma_f32_16x16x32_bf16(af[mt], bfr[nt], acc[mt][nt], 0, 0, 0);
  }

  const int sel = n0 >> 10;                 // 0=Q, 1=K, 2=V (block-uniform)
#pragma unroll
  for (int mt = 0; mt < 4; mt++) {
#pragma unroll
    for (int r = 0; r < 4; r++) {
      int row = m0 + wm + mt * 16 + quad * 4 + r;
#pragma unroll
      for (int nt = 0; nt < 4; nt++) {
        int col = n0 + wn + nt * 16 + lc;
        ushort v = f2bf(acc[mt][nt][r]);
        if (sel < 2) {
          QK[((size_t)sel << 22) + (size_t)row * 1024 + (col & 1023)] = v;
        } else {
          // Vt[bh][d][t]: bh = (row>>11)*16 + (hd>>6), d = hd&63, t = row&2047
          int hd = col & 1023;
          size_t bh = (size_t)((row >> 11) * 16 + (hd >> 6));
          Vt[bh * 131072 + (size_t)(hd & 63) * 2048 + (row & 2047)] = v;
        }
      }
    }
  }
}

// ---------------- proj GEMM: out[4096][1024] = attn_out @ Wo^T + bo ----------------
// BM=128, BN=64, BK=64 (two proven BK=32 half-tiles per barrier), dbuf global_load_lds.
__global__ __launch_bounds__(256) void gemm_proj(const ushort* __restrict__ A,
                                                 const ushort* __restrict__ B,
                                                 float* __restrict__ C,
                                                 const float* __restrict__ bias) {
  const int K = 1024;
  __shared__ __align__(16) ushort As[2][2][128 * 32];  // [buf][k-half][row][32]
  __shared__ __align__(16) ushort Bs[2][2][64 * 32];
  const int m0 = blockIdx.y * 128, n0 = blockIdx.x * 64;
  const int tid = threadIdx.x, lane = tid & 63, wid = tid >> 6;
  const int quad = lane >> 4, lc = lane & 15;
  const int lrow = lane >> 2, lcol = (lane & 3) * 8;
  const int wm = (wid >> 1) * 64, wn = (wid & 1) * 32;

  f32x4 acc[4][2] = {};

  auto stage = [&](int k0, int nb) {
    const ushort* Ag = A + (size_t)(m0 + wid * 32 + lrow) * K + k0 + lcol;
    g2l16(Ag,                      &As[nb][0][wid * 1024]);
    g2l16(Ag + (size_t)16 * K,     &As[nb][0][wid * 1024 + 512]);
    g2l16(Ag + 32,                 &As[nb][1][wid * 1024]);
    g2l16(Ag + (size_t)16 * K + 32, &As[nb][1][wid * 1024 + 512]);
    const ushort* Bg = B + (size_t)(n0 + wid * 16 + lrow) * K + k0 + lcol;
    g2l16(Bg,      &Bs[nb][0][wid * 512]);
    g2l16(Bg + 32, &Bs[nb][1][wid * 512]);
  };

  stage(0, 0);
  for (int k0 = 0; k0 < K; k0 += 64) {
    const int nb = (k0 >> 6) & 1;
    __syncthreads();
    if (k0 + 64 < K) stage(k0 + 64, nb ^ 1);

#pragma unroll
    for (int ks = 0; ks < 2; ks++) {
      bf16x8 af[4], bfr[2];
#pragma unroll
      for (int t = 0; t < 4; t++)
        af[t] = *(const bf16x8*)&As[nb][ks][(wm + t * 16 + lc) * 32 + quad * 8];
#pragma unroll
      for (int t = 0; t < 2; t++)
        bfr[t] = *(const bf16x8*)&Bs[nb][ks][(wn + t * 16 + lc) * 32 + quad * 8];
#pragma unroll
      for (int mt = 0; mt < 4; mt++)
#pragma unroll
        for (int nt = 0; nt < 2; nt++)
          acc[mt][nt] = __builtin_amdgcn_mfma_f32_16x16x32_bf16(af[mt], bfr[nt], acc[mt][nt], 0, 0, 0);
    }
  }

#pragma unroll
  for (int mt = 0; mt < 4; mt++) {
#pragma unroll
    for (int r = 0; r < 4; r++) {
      int row = m0 + wm + mt * 16 + quad * 4 + r;
#pragma unroll
      for (int nt = 0; nt < 2; nt++) {
        int col = n0 + wn + nt * 16 + lc;
        C[(size_t)row * 1024 + col] = acc[mt][nt][r] + bias[col];
      }
    }
  }
}

// ---------------- chunked flash attention (causal, no-max softmax) — round-4 proven ----------------
// Grid (80, 32): blockIdx.y = bh; blockIdx.x -> (q-block qi of 64 queries, key-chunk ci of
// <=512 keys). Partial (O_unnorm fp32, l fp32) accumulated via atomicAdd: O32 = d_out scratch.
// Chunks combine by pure addition (no running max). 4 waves, 16 q/wave.
__global__ __launch_bounds__(256, 6) void attn_kernel(const ushort* __restrict__ Qb,
                                                      const ushort* __restrict__ Kb,
                                                      const ushort* __restrict__ Vt,
                                                      float* __restrict__ O32,
                                                      float* __restrict__ L32) {
  __shared__ __align__(16) ushort Ks[2][64 * 32];   // [d-half][key 64][d 32]
  __shared__ __align__(16) ushort Vs[2][64 * 32];   // [k-half][d 64][k 32]
  __shared__ __align__(16) ushort Ps[4][16][72];    // per-wave P tile [q 16][k 64+pad]

  const int bh = blockIdx.y, b = bh >> 4, h = bh & 15;
  // decode chunk id, heavy (8-tile) chunks first
  const int f = 79 - (int)blockIdx.x;
  int qi, ci;
  if (f < 8)       { qi = f;                 ci = 0; }
  else if (f < 24) { int g = f - 8;  qi = 8  + (g >> 1); ci = g & 1; }
  else if (f < 48) { int g = f - 24; int q3 = g / 3; qi = 16 + q3; ci = g - 3 * q3; }
  else             { int g = f - 48; qi = 24 + (g >> 2); ci = g & 3; }

  const int t0 = ci * 8;
  const int t1 = min(t0 + 8, qi + 1);
  const int qb_block = qi * 64;

  const int tid = threadIdx.x, lane = tid & 63, wid = tid >> 6;
  const int quad = lane >> 4, lc = lane & 15;
  const int lrow = lane >> 2, lcol = (lane & 3) * 8;
  const int qbw = qb_block + wid * 16;

  const size_t kbase = (size_t)(b * 2048) * 1024 + h * 64;
  const size_t vbase = (size_t)bh * 131072;

  // Q fragments (A-layout), resident
  const ushort* Qp = Qb + kbase + (size_t)(qbw + lc) * 1024;
  bf16x8 qf0 = *(const bf16x8*)(Qp + quad * 8);
  bf16x8 qf1 = *(const bf16x8*)(Qp + 32 + quad * 8);

  f32x4 o_acc[4] = {};
  float l_r[4] = {0.f, 0.f, 0.f, 0.f};

  for (int kt = t0; kt < t1; kt++) {
    const int kb = kt * 64;
    __syncthreads();
#pragma unroll
    for (int cc = 0; cc < 2; cc++) {
      int ck = wid + cc * 4;
      int half = ck >> 2, rg = ck & 3;
      const ushort* gK = Kb + kbase + (size_t)(kb + rg * 16 + lrow) * 1024 + half * 32 + lcol;
      g2l16(gK, &Ks[half][rg * 512]);
      const ushort* gV = Vt + vbase + (size_t)(rg * 16 + lrow) * 2048 + kb + half * 32 + lcol;
      g2l16(gV, &Vs[half][rg * 512]);
    }
    __syncthreads();

    // S = Q K^T (16 q x 64 k), mask, exp2, scatter P
    const bool diag = (kb + 63 > qbw);
#pragma unroll
    for (int c = 0; c < 4; c++) {
      bf16x8 kf0 = *(const bf16x8*)&Ks[0][(c * 16 + lc) * 32 + quad * 8];
      bf16x8 kf1 = *(const bf16x8*)&Ks[1][(c * 16 + lc) * 32 + quad * 8];
      f32x4 z = {};
      z = __builtin_amdgcn_mfma_f32_16x16x32_bf16(qf0, kf0, z, 0, 0, 0);
      z = __builtin_amdgcn_mfma_f32_16x16x32_bf16(qf1, kf1, z, 0, 0, 0);
#pragma unroll
      for (int r = 0; r < 4; r++) {
        float sv = z[r];
        if (diag && (kb + c * 16 + lc > qbw + quad * 4 + r)) sv = -1e30f;
        float pv = __builtin_amdgcn_exp2f(sv);    // log2e pre-folded into Wq
        l_r[r] += pv;
        Ps[wid][quad * 4 + r][c * 16 + lc] = f2bf(pv);
      }
    }
    __asm__ volatile("s_waitcnt lgkmcnt(0)" ::: "memory");
    bf16x8 ap0 = *(const bf16x8*)&Ps[wid][lc][quad * 8];
    bf16x8 ap1 = *(const bf16x8*)&Ps[wid][lc][32 + quad * 8];

    // O += P V
#pragma unroll
    for (int nt = 0; nt < 4; nt++) {
      bf16x8 vb0 = *(const bf16x8*)&Vs[0][(nt * 16 + lc) * 32 + quad * 8];
      bf16x8 vb1 = *(const bf16x8*)&Vs[1][(nt * 16 + lc) * 32 + quad * 8];
      o_acc[nt] = __builtin_amdgcn_mfma_f32_16x16x32_bf16(ap0, vb0, o_acc[nt], 0, 0, 0);
      o_acc[nt] = __builtin_amdgcn_mfma_f32_16x16x32_bf16(ap1, vb1, o_acc[nt], 0, 0, 0);
    }
  }

  // reduce l across the 16 lanes of each quad group, then atomics
#pragma unroll
  for (int r = 0; r < 4; r++) {
    float s_ = l_r[r];
    s_ += __shfl_xor(s_, 1);
    s_ += __shfl_xor(s_, 2);
    s_ += __shfl_xor(s_, 4);
    s_ += __shfl_xor(s_, 8);
    l_r[r] = s_;
  }
  if (lc == 0) {
#pragma unroll
    for (int r = 0; r < 4; r++)
      atomicAdd(&L32[(size_t)bh * 2048 + qbw + quad * 4 + r], l_r[r]);
  }
#pragma unroll
  for (int r = 0; r < 4; r++) {
    size_t orow = ((size_t)(b * 2048) + qbw + quad * 4 + r) * 1024 + h * 64 + lc;
#pragma unroll
    for (int nt = 0; nt < 4; nt++)
      atomicAdd(&O32[orow + nt * 16], o_acc[nt][r]);
  }
}

// ---------------- normalize: O32/l -> bf16 attn_out ----------------
__global__ __launch_bounds__(256) void normalize_kernel(const float* __restrict__ O32,
                                                        const float* __restrict__ L32,
                                                        ushort* __restrict__ Out) {
  const int row = blockIdx.x;            // 0..4095  (b*2048 + t)
  const int tid = threadIdx.x;
  const int col = tid * 4;
  const int b = row >> 11, t = row & 2047, h = col >> 6;
  const float inv = 1.0f / L32[(size_t)(b * 16 + h) * 2048 + t];
  float4 o = ((const float4*)(O32 + (size_t)row * 1024))[tid];
  ushort4 u;
  u.x = f2bf(o.x * inv); u.y = f2bf(o.y * inv);
  u.z = f2bf(o.z * inv); u.w = f2bf(o.w * inv);
  ((ushort4*)(Out + (size_t)row * 1024))[tid] = u;
}

// ---------------- launcher ----------------
extern "C" void kernel_launch(void* const* d_in, const int* in_sizes, int n_in,
                              void* d_out, int out_size, void* d_ws, size_t ws_size,
                              hipStream_t stream) {
  const float* x  = (const float*)d_in[0];
  const float* Wq = (const float*)d_in[1];
  const float* Wk = (const float*)d_in[2];
  const float* Wv = (const float*)d_in[3];
  const float* Wo = (const float*)d_in[4];
  const float* bo = (const float*)d_in[5];
  float* out = (float*)d_out;

  char* ws = (char*)d_ws;
  ushort* xbf  = (ushort*)(ws);                  //  8 MB: x bf16 (dead after gemm_qkv)
  ushort* wcat = (ushort*)(ws + (8ull  << 20));  //  8 MB: Wcat bf16
  ushort* qkv  = (ushort*)(ws + (16ull << 20));  // 24 MB: Q | K | Vt planes
  ushort* Qp   = qkv;
  ushort* Kp   = qkv + (1ull << 22);
  ushort* Vt   = qkv + (2ull << 22);             // V written directly transposed
  float*  L32  = (float*)ws;                     // 256 KB over dead xbf
  float*  O32  = out;                            // d_out as fp32 accumulator scratch
  ushort* attn_out = Qp;                         // Q plane free after attn

  cast_all<<<8192, 256, 0, stream>>>(x, Wq, Wk, Wv, Wo, xbf, wcat);

  // QKV = x @ Wcat[0:3072]^T; Q pre-scaled by 0.125*log2e; V transposed in epilogue
  gemm_qkv<<<dim3(24, 32), 256, 0, stream>>>(xbf, wcat, qkv, Vt);

  hipMemsetAsync(L32, 0, (size_t)32 * 2048 * 4, stream);
  hipMemsetAsync(O32, 0, (size_t)4096 * 1024 * 4, stream);

  attn_kernel<<<dim3(80, 32), 256, 0, stream>>>(Qp, Kp, Vt, O32, L32);

  normalize_kernel<<<4096, 256, 0, stream>>>(O32, L32, attn_out);

  // out = attn_out @ Wo^T + bo   (overwrites O32 scratch, stream-ordered)
  gemm_proj<<<dim3(16, 32), 256, 0, stream>>>(
      attn_out, wcat + (size_t)3072 * 1024, out, bo);
}

// Round 7
// 212.477 us; speedup vs baseline: 1.0162x; 1.0162x over previous
//
#include <hip/hip_runtime.h>
#include <math.h>

typedef __attribute__((ext_vector_type(8))) short bf16x8;
typedef __attribute__((ext_vector_type(4))) float f32x4;

__device__ __forceinline__ ushort f2bf(float f) {
  union { float f; unsigned u; } v; v.f = f;
  return (ushort)((v.u + 0x8000u) >> 16);
}

// async global->LDS, 16B per lane. lds base wave-uniform; lane i lands at base + i*16B.
__device__ __forceinline__ void g2l16(const void* g, void* l) {
  __builtin_amdgcn_global_load_lds((const __attribute__((address_space(1))) unsigned*)g,
                                   (__attribute__((address_space(3))) unsigned*)l, 16, 0, 0);
}

// ---------------- merged cast + zero kernel ----------------
// idx [0,1M): x -> xbf.  [1M,2M): weights -> wcat (Wq scaled).  [2M,3M): zero O32.
__global__ __launch_bounds__(256) void cast_all(const float* __restrict__ x,
                                                const float* __restrict__ Wq,
                                                const float* __restrict__ Wk,
                                                const float* __restrict__ Wv,
                                                const float* __restrict__ Wo,
                                                ushort* __restrict__ xbf,
                                                ushort* __restrict__ wcat,
                                                float4* __restrict__ O32) {
  int i = blockIdx.x * 256 + threadIdx.x;
  if (i < 1048576) {
    float4 v = ((const float4*)x)[i];
    ushort4 u; u.x = f2bf(v.x); u.y = f2bf(v.y); u.z = f2bf(v.z); u.w = f2bf(v.w);
    ((ushort4*)xbf)[i] = u;
  } else if (i < 2097152) {
    int j = i - 1048576;
    int sel = j >> 18;
    const float* src = (sel == 0) ? Wq : (sel == 1) ? Wk : (sel == 2) ? Wv : Wo;
    float scale = (sel == 0) ? 0.125f * 1.44269504088896f : 1.0f;  // fold D^-0.5 * log2e
    float4 v = ((const float4*)src)[j & 0x3FFFF];
    ushort4 u;
    u.x = f2bf(v.x * scale); u.y = f2bf(v.y * scale);
    u.z = f2bf(v.z * scale); u.w = f2bf(v.w * scale);
    ((ushort4*)wcat)[j] = u;
  } else {
    O32[i - 2097152] = float4{0.f, 0.f, 0.f, 0.f};
  }
}

// ---------------- QKV GEMM: C = A @ B^T, 128x128, BK=32, dbuf (round-4 proven) ----------------
// Output split into 3 planes of [4096][1024] (Q | K | V).
__global__ __launch_bounds__(256) void gemm_qkv(const ushort* __restrict__ A,
                                                const ushort* __restrict__ B,
                                                ushort* __restrict__ C3) {
  const int K = 1024;
  __shared__ __align__(16) ushort As[2][128 * 32];
  __shared__ __align__(16) ushort Bs[2][128 * 32];
  const int m0 = blockIdx.y * 128, n0 = blockIdx.x * 128;
  const int tid = threadIdx.x, lane = tid & 63, wid = tid >> 6;
  const int quad = lane >> 4, lc = lane & 15;
  const int lrow = lane >> 2, lcol = (lane & 3) * 8;
  const int wm = (wid >> 1) * 64, wn = (wid & 1) * 64;

  f32x4 acc[4][4] = {};

  auto stage = [&](int k0, int nb) {
    const ushort* Ag = A + (size_t)(m0 + wid * 32 + lrow) * K + k0 + lcol;
    g2l16(Ag, &As[nb][wid * 1024]);
    g2l16(Ag + (size_t)16 * K, &As[nb][wid * 1024 + 512]);
    const ushort* Bg = B + (size_t)(n0 + wid * 32 + lrow) * K + k0 + lcol;
    g2l16(Bg, &Bs[nb][wid * 1024]);
    g2l16(Bg + (size_t)16 * K, &Bs[nb][wid * 1024 + 512]);
  };

  stage(0, 0);
  for (int k0 = 0; k0 < K; k0 += 32) {
    const int nb = (k0 >> 5) & 1;
    __syncthreads();
    if (k0 + 32 < K) stage(k0 + 32, nb ^ 1);

    bf16x8 af[4], bfr[4];
#pragma unroll
    for (int t = 0; t < 4; t++)
      af[t] = *(const bf16x8*)&As[nb][(wm + t * 16 + lc) * 32 + quad * 8];
#pragma unroll
    for (int t = 0; t < 4; t++)
      bfr[t] = *(const bf16x8*)&Bs[nb][(wn + t * 16 + lc) * 32 + quad * 8];
#pragma unroll
    for (int mt = 0; mt < 4; mt++)
#pragma unroll
      for (int nt = 0; nt < 4; nt++)
        acc[mt][nt] = __builtin_amdgcn_mfma_f32_16x16x32_bf16(af[mt], bfr[nt], acc[mt][nt], 0, 0, 0);
  }

#pragma unroll
  for (int mt = 0; mt < 4; mt++) {
#pragma unroll
    for (int r = 0; r < 4; r++) {
      int row = m0 + wm + mt * 16 + quad * 4 + r;
#pragma unroll
      for (int nt = 0; nt < 4; nt++) {
        int col = n0 + wn + nt * 16 + lc;
        size_t dst = ((size_t)(col >> 10) << 22) + (size_t)row * 1024 + (col & 1023);
        C3[dst] = f2bf(acc[mt][nt][r]);
      }
    }
  }
}

// ---------------- proj GEMM: out[4096][1024] = attn_out @ Wo^T + bo, BK=64 ----------------
__global__ __launch_bounds__(256) void gemm_proj(const ushort* __restrict__ A,
                                                 const ushort* __restrict__ B,
                                                 float* __restrict__ C,
                                                 const float* __restrict__ bias) {
  const int K = 1024;
  __shared__ __align__(16) ushort As[2][2][128 * 32];  // [buf][k-half][row][32]
  __shared__ __align__(16) ushort Bs[2][2][64 * 32];
  const int m0 = blockIdx.y * 128, n0 = blockIdx.x * 64;
  const int tid = threadIdx.x, lane = tid & 63, wid = tid >> 6;
  const int quad = lane >> 4, lc = lane & 15;
  const int lrow = lane >> 2, lcol = (lane & 3) * 8;
  const int wm = (wid >> 1) * 64, wn = (wid & 1) * 32;

  f32x4 acc[4][2] = {};

  auto stage = [&](int k0, int nb) {
    const ushort* Ag = A + (size_t)(m0 + wid * 32 + lrow) * K + k0 + lcol;
    g2l16(Ag,                       &As[nb][0][wid * 1024]);
    g2l16(Ag + (size_t)16 * K,      &As[nb][0][wid * 1024 + 512]);
    g2l16(Ag + 32,                  &As[nb][1][wid * 1024]);
    g2l16(Ag + (size_t)16 * K + 32, &As[nb][1][wid * 1024 + 512]);
    const ushort* Bg = B + (size_t)(n0 + wid * 16 + lrow) * K + k0 + lcol;
    g2l16(Bg,      &Bs[nb][0][wid * 512]);
    g2l16(Bg + 32, &Bs[nb][1][wid * 512]);
  };

  stage(0, 0);
  for (int k0 = 0; k0 < K; k0 += 64) {
    const int nb = (k0 >> 6) & 1;
    __syncthreads();
    if (k0 + 64 < K) stage(k0 + 64, nb ^ 1);

#pragma unroll
    for (int ks = 0; ks < 2; ks++) {
      bf16x8 af[4], bfr[2];
#pragma unroll
      for (int t = 0; t < 4; t++)
        af[t] = *(const bf16x8*)&As[nb][ks][(wm + t * 16 + lc) * 32 + quad * 8];
#pragma unroll
      for (int t = 0; t < 2; t++)
        bfr[t] = *(const bf16x8*)&Bs[nb][ks][(wn + t * 16 + lc) * 32 + quad * 8];
#pragma unroll
      for (int mt = 0; mt < 4; mt++)
#pragma unroll
        for (int nt = 0; nt < 2; nt++)
          acc[mt][nt] = __builtin_amdgcn_mfma_f32_16x16x32_bf16(af[mt], bfr[nt], acc[mt][nt], 0, 0, 0);
    }
  }

#pragma unroll
  for (int mt = 0; mt < 4; mt++) {
#pragma unroll
    for (int r = 0; r < 4; r++) {
      int row = m0 + wm + mt * 16 + quad * 4 + r;
#pragma unroll
      for (int nt = 0; nt < 2; nt++) {
        int col = n0 + wn + nt * 16 + lc;
        C[(size_t)row * 1024 + col] = acc[mt][nt][r] + bias[col];
      }
    }
  }
}

// ---------------- V transpose: Vb[4096][1024] -> Vt[bh=32][d=64][t=2048] ----------------
__global__ __launch_bounds__(256) void transpose_v(const ushort* __restrict__ Vb,
                                                   ushort* __restrict__ Vt) {
  __shared__ ushort tile[64][72];
  const int bh = blockIdx.y, b = bh >> 4, h = bh & 15;
  const int tt = blockIdx.x;
  const int tid = threadIdx.x;
#pragma unroll
  for (int i = 0; i < 2; i++) {
    int idx = i * 256 + tid;
    int trow = idx >> 3;
    int dcol = (idx & 7) * 8;
    uint4 v = *(const uint4*)(Vb + (size_t)(b * 2048 + tt * 64 + trow) * 1024 + h * 64 + dcol);
    ushort e[8]; *(uint4*)e = v;
#pragma unroll
    for (int j = 0; j < 8; j++) tile[dcol + j][trow] = e[j];
  }
  __syncthreads();
#pragma unroll
  for (int i = 0; i < 2; i++) {
    int idx = i * 256 + tid;
    int drow = idx >> 3;
    int tloc = (idx & 7) * 8;
    uint4 v = *(const uint4*)&tile[drow][tloc];
    *(uint4*)(Vt + (size_t)bh * 131072 + (size_t)drow * 2048 + tt * 64 + tloc) = v;
  }
}

// ---------------- chunked flash attention (causal, no-max softmax), 32 q/wave ----------------
// Grid (40, 32): blockIdx.y = bh; blockIdx.x -> (128-query block qi, key-chunk ci of <=8
// key-tiles of 64). Partials (O_unnorm fp32, l) combine by addition via atomicAdd.
// 4 waves x 32 q; K/V staged via global_load_lds; P C->A via per-wave LDS.
__global__ __launch_bounds__(256, 4) void attn_kernel(const ushort* __restrict__ Qb,
                                                      const ushort* __restrict__ Kb,
                                                      const ushort* __restrict__ Vt,
                                                      float* __restrict__ O32,
                                                      float* __restrict__ L32) {
  __shared__ __align__(16) ushort Ks[2][64 * 32];   // [d-half][key 64][d 32]
  __shared__ __align__(16) ushort Vs[2][64 * 32];   // [k-half][d 64][k 32]
  __shared__ __align__(16) ushort Ps[4][32][72];    // per-wave P tile [q 32][k 64+pad]

  const int bh = blockIdx.y, b = bh >> 4, h = bh & 15;
  // decode (qi, ci): low blockIdx.x = heaviest q-blocks first
  const int f = (int)blockIdx.x;
  int qi, ci;
  if (f < 16)      { qi = 12 + (f >> 2); ci = f & 3; }
  else if (f < 28) { int g = f - 16; int q3 = g / 3; qi = 8 + q3; ci = g - 3 * q3; }
  else if (f < 36) { int g = f - 28; qi = 4 + (g >> 1); ci = g & 1; }
  else             { qi = f - 36; ci = 0; }
  const int t0 = ci * 8;
  const int t1 = min(t0 + 8, 2 * qi + 2);

  const int tid = threadIdx.x, lane = tid & 63, wid = tid >> 6;
  const int quad = lane >> 4, lc = lane & 15;
  const int lrow = lane >> 2, lcol = (lane & 3) * 8;
  const int qbw = qi * 128 + wid * 32;

  const size_t kbase = (size_t)(b * 2048) * 1024 + h * 64;
  const size_t vbase = (size_t)bh * 131072;

  // Q fragments (A-layout), resident: 2 q-tiles x 2 k-halves
  bf16x8 qf[2][2];
#pragma unroll
  for (int t = 0; t < 2; t++) {
    const ushort* Qp = Qb + kbase + (size_t)(qbw + t * 16 + lc) * 1024;
    qf[t][0] = *(const bf16x8*)(Qp + quad * 8);
    qf[t][1] = *(const bf16x8*)(Qp + 32 + quad * 8);
  }

  f32x4 o_acc[2][4] = {};
  float l_r[2][4] = {};

  for (int kt = t0; kt < t1; kt++) {
    const int kb = kt * 64;
    __syncthreads();
#pragma unroll
    for (int cc = 0; cc < 2; cc++) {
      int ck = wid + cc * 4;
      int half = ck >> 2, rg = ck & 3;
      const ushort* gK = Kb + kbase + (size_t)(kb + rg * 16 + lrow) * 1024 + half * 32 + lcol;
      g2l16(gK, &Ks[half][rg * 512]);
      const ushort* gV = Vt + vbase + (size_t)(rg * 16 + lrow) * 2048 + kb + half * 32 + lcol;
      g2l16(gV, &Vs[half][rg * 512]);
    }
    __syncthreads();

    // S = Q K^T (2 q-tiles x 64 keys), mask, exp2, scatter P
#pragma unroll
    for (int c = 0; c < 4; c++) {
      bf16x8 kf0 = *(const bf16x8*)&Ks[0][(c * 16 + lc) * 32 + quad * 8];
      bf16x8 kf1 = *(const bf16x8*)&Ks[1][(c * 16 + lc) * 32 + quad * 8];
#pragma unroll
      for (int t = 0; t < 2; t++) {
        f32x4 z = {};
        z = __builtin_amdgcn_mfma_f32_16x16x32_bf16(qf[t][0], kf0, z, 0, 0, 0);
        z = __builtin_amdgcn_mfma_f32_16x16x32_bf16(qf[t][1], kf1, z, 0, 0, 0);
        const bool diag = (kb + 63 > qbw + t * 16);   // wave-uniform
#pragma unroll
        for (int r = 0; r < 4; r++) {
          float sv = z[r];
          if (diag && (kb + c * 16 + lc > qbw + t * 16 + quad * 4 + r)) sv = -1e30f;
          float pv = __builtin_amdgcn_exp2f(sv);     // log2e pre-folded into Wq
          l_r[t][r] += pv;
          Ps[wid][t * 16 + quad * 4 + r][c * 16 + lc] = f2bf(pv);
        }
      }
    }
    __asm__ volatile("s_waitcnt lgkmcnt(0)" ::: "memory");  // wave-local P ordering
    bf16x8 ap[2][2];
#pragma unroll
    for (int t = 0; t < 2; t++) {
      ap[t][0] = *(const bf16x8*)&Ps[wid][t * 16 + lc][quad * 8];
      ap[t][1] = *(const bf16x8*)&Ps[wid][t * 16 + lc][32 + quad * 8];
    }

    // O += P V (V fragments shared across both q-tiles)
#pragma unroll
    for (int nt = 0; nt < 4; nt++) {
      bf16x8 vb0 = *(const bf16x8*)&Vs[0][(nt * 16 + lc) * 32 + quad * 8];
      bf16x8 vb1 = *(const bf16x8*)&Vs[1][(nt * 16 + lc) * 32 + quad * 8];
#pragma unroll
      for (int t = 0; t < 2; t++) {
        o_acc[t][nt] = __builtin_amdgcn_mfma_f32_16x16x32_bf16(ap[t][0], vb0, o_acc[t][nt], 0, 0, 0);
        o_acc[t][nt] = __builtin_amdgcn_mfma_f32_16x16x32_bf16(ap[t][1], vb1, o_acc[t][nt], 0, 0, 0);
      }
    }
  }

  // reduce l across the 16 lanes of each quad group, then atomics
#pragma unroll
  for (int t = 0; t < 2; t++) {
#pragma unroll
    for (int r = 0; r < 4; r++) {
      float s_ = l_r[t][r];
      s_ += __shfl_xor(s_, 1);
      s_ += __shfl_xor(s_, 2);
      s_ += __shfl_xor(s_, 4);
      s_ += __shfl_xor(s_, 8);
      l_r[t][r] = s_;
    }
    if (lc == 0) {
#pragma unroll
      for (int r = 0; r < 4; r++)
        atomicAdd(&L32[(size_t)bh * 2048 + qbw + t * 16 + quad * 4 + r], l_r[t][r]);
    }
#pragma unroll
    for (int r = 0; r < 4; r++) {
      size_t orow = ((size_t)(b * 2048) + qbw + t * 16 + quad * 4 + r) * 1024 + h * 64 + lc;
#pragma unroll
      for (int nt = 0; nt < 4; nt++)
        atomicAdd(&O32[orow + nt * 16], o_acc[t][nt][r]);
    }
  }
}

// ---------------- normalize: O32/l -> bf16 attn_out ----------------
__global__ __launch_bounds__(256) void normalize_kernel(const float* __restrict__ O32,
                                                        const float* __restrict__ L32,
                                                        ushort* __restrict__ Out) {
  const int row = blockIdx.x;            // 0..4095  (b*2048 + t)
  const int tid = threadIdx.x;
  const int col = tid * 4;
  const int b = row >> 11, t = row & 2047, h = col >> 6;
  const float inv = 1.0f / L32[(size_t)(b * 16 + h) * 2048 + t];
  float4 o = ((const float4*)(O32 + (size_t)row * 1024))[tid];
  ushort4 u;
  u.x = f2bf(o.x * inv); u.y = f2bf(o.y * inv);
  u.z = f2bf(o.z * inv); u.w = f2bf(o.w * inv);
  ((ushort4*)(Out + (size_t)row * 1024))[tid] = u;
}

// ---------------- launcher ----------------
extern "C" void kernel_launch(void* const* d_in, const int* in_sizes, int n_in,
                              void* d_out, int out_size, void* d_ws, size_t ws_size,
                              hipStream_t stream) {
  const float* x  = (const float*)d_in[0];
  const float* Wq = (const float*)d_in[1];
  const float* Wk = (const float*)d_in[2];
  const float* Wv = (const float*)d_in[3];
  const float* Wo = (const float*)d_in[4];
  const float* bo = (const float*)d_in[5];
  float* out = (float*)d_out;

  char* ws = (char*)d_ws;
  ushort* xbf  = (ushort*)(ws);                  //  8 MB: x bf16 (dead after gemm_qkv)
  ushort* wcat = (ushort*)(ws + (8ull  << 20));  //  8 MB: Wcat bf16
  ushort* qkv  = (ushort*)(ws + (16ull << 20));  // 24 MB: Q | K | V planes
  ushort* Qp   = qkv;
  ushort* Kp   = qkv + (1ull << 22);
  ushort* Vp   = qkv + (2ull << 22);
  ushort* Vt   = (ushort*)(ws);                  //  8 MB: V^T over dead xbf
  float*  L32  = (float*)Vp;                     // 256 KB in V plane (free after transpose)
  float*  O32  = out;                            // d_out as fp32 accumulator scratch
  ushort* attn_out = Qp;                         // Q plane free after attn

  // cast x+weights, zero O32 (12288 blocks = 3M threads)
  cast_all<<<12288, 256, 0, stream>>>(x, Wq, Wk, Wv, Wo, xbf, wcat, (float4*)O32);

  // QKV = x @ Wcat[0:3072]^T -> 3 planes (Q pre-scaled by 0.125*log2e)
  gemm_qkv<<<dim3(24, 32), 256, 0, stream>>>(xbf, wcat, qkv);

  transpose_v<<<dim3(32, 32), 256, 0, stream>>>(Vp, Vt);

  hipMemsetAsync(L32, 0, (size_t)32 * 2048 * 4, stream);

  attn_kernel<<<dim3(40, 32), 256, 0, stream>>>(Qp, Kp, Vt, O32, L32);

  normalize_kernel<<<4096, 256, 0, stream>>>(O32, L32, attn_out);

  // out = attn_out @ Wo^T + bo   (overwrites O32 scratch, stream-ordered)
  gemm_proj<<<dim3(16, 32), 256, 0, stream>>>(
      attn_out, wcat + (size_t)3072 * 1024, out, bo);
}

// Round 8
// 206.162 us; speedup vs baseline: 1.0474x; 1.0306x over previous
//
#include <hip/hip_runtime.h>
#include <math.h>

typedef __attribute__((ext_vector_type(8))) short bf16x8;
typedef __attribute__((ext_vector_type(4))) float f32x4;

__device__ __forceinline__ ushort f2bf(float f) {
  union { float f; unsigned u; } v; v.f = f;
  return (ushort)((v.u + 0x8000u) >> 16);
}

// async global->LDS, 16B per lane. lds base wave-uniform; lane i lands at base + i*16B.
__device__ __forceinline__ void g2l16(const void* g, void* l) {
  __builtin_amdgcn_global_load_lds((const __attribute__((address_space(1))) unsigned*)g,
                                   (__attribute__((address_space(3))) unsigned*)l, 16, 0, 0);
}

// ---------------- merged cast + zero kernel ----------------
// idx [0,1M): x -> xbf.  [1M,2M): weights -> wcat (Wq scaled).  [2M,3M): zero O32.
__global__ __launch_bounds__(256) void cast_all(const float* __restrict__ x,
                                                const float* __restrict__ Wq,
                                                const float* __restrict__ Wk,
                                                const float* __restrict__ Wv,
                                                const float* __restrict__ Wo,
                                                ushort* __restrict__ xbf,
                                                ushort* __restrict__ wcat,
                                                float4* __restrict__ O32) {
  int i = blockIdx.x * 256 + threadIdx.x;
  if (i < 1048576) {
    float4 v = ((const float4*)x)[i];
    ushort4 u; u.x = f2bf(v.x); u.y = f2bf(v.y); u.z = f2bf(v.z); u.w = f2bf(v.w);
    ((ushort4*)xbf)[i] = u;
  } else if (i < 2097152) {
    int j = i - 1048576;
    int sel = j >> 18;
    const float* src = (sel == 0) ? Wq : (sel == 1) ? Wk : (sel == 2) ? Wv : Wo;
    float scale = (sel == 0) ? 0.125f * 1.44269504088896f : 1.0f;  // fold D^-0.5 * log2e
    float4 v = ((const float4*)src)[j & 0x3FFFF];
    ushort4 u;
    u.x = f2bf(v.x * scale); u.y = f2bf(v.y * scale);
    u.z = f2bf(v.z * scale); u.w = f2bf(v.w * scale);
    ((ushort4*)wcat)[j] = u;
  } else {
    O32[i - 2097152] = float4{0.f, 0.f, 0.f, 0.f};
  }
}

// ---------------- QKV GEMM: C = A @ B^T, 128x128, BK=32, dbuf (proven) ----------------
__global__ __launch_bounds__(256) void gemm_qkv(const ushort* __restrict__ A,
                                                const ushort* __restrict__ B,
                                                ushort* __restrict__ C3) {
  const int K = 1024;
  __shared__ __align__(16) ushort As[2][128 * 32];
  __shared__ __align__(16) ushort Bs[2][128 * 32];
  const int m0 = blockIdx.y * 128, n0 = blockIdx.x * 128;
  const int tid = threadIdx.x, lane = tid & 63, wid = tid >> 6;
  const int quad = lane >> 4, lc = lane & 15;
  const int lrow = lane >> 2, lcol = (lane & 3) * 8;
  const int wm = (wid >> 1) * 64, wn = (wid & 1) * 64;

  f32x4 acc[4][4] = {};

  auto stage = [&](int k0, int nb) {
    const ushort* Ag = A + (size_t)(m0 + wid * 32 + lrow) * K + k0 + lcol;
    g2l16(Ag, &As[nb][wid * 1024]);
    g2l16(Ag + (size_t)16 * K, &As[nb][wid * 1024 + 512]);
    const ushort* Bg = B + (size_t)(n0 + wid * 32 + lrow) * K + k0 + lcol;
    g2l16(Bg, &Bs[nb][wid * 1024]);
    g2l16(Bg + (size_t)16 * K, &Bs[nb][wid * 1024 + 512]);
  };

  stage(0, 0);
  for (int k0 = 0; k0 < K; k0 += 32) {
    const int nb = (k0 >> 5) & 1;
    __syncthreads();
    if (k0 + 32 < K) stage(k0 + 32, nb ^ 1);

    bf16x8 af[4], bfr[4];
#pragma unroll
    for (int t = 0; t < 4; t++)
      af[t] = *(const bf16x8*)&As[nb][(wm + t * 16 + lc) * 32 + quad * 8];
#pragma unroll
    for (int t = 0; t < 4; t++)
      bfr[t] = *(const bf16x8*)&Bs[nb][(wn + t * 16 + lc) * 32 + quad * 8];
#pragma unroll
    for (int mt = 0; mt < 4; mt++)
#pragma unroll
      for (int nt = 0; nt < 4; nt++)
        acc[mt][nt] = __builtin_amdgcn_mfma_f32_16x16x32_bf16(af[mt], bfr[nt], acc[mt][nt], 0, 0, 0);
  }

#pragma unroll
  for (int mt = 0; mt < 4; mt++) {
#pragma unroll
    for (int r = 0; r < 4; r++) {
      int row = m0 + wm + mt * 16 + quad * 4 + r;
#pragma unroll
      for (int nt = 0; nt < 4; nt++) {
        int col = n0 + wn + nt * 16 + lc;
        size_t dst = ((size_t)(col >> 10) << 22) + (size_t)row * 1024 + (col & 1023);
        C3[dst] = f2bf(acc[mt][nt][r]);
      }
    }
  }
}

// ---------------- proj GEMM: out[4096][1024] = attn_out @ Wo^T + bo, BK=64 ----------------
__global__ __launch_bounds__(256) void gemm_proj(const ushort* __restrict__ A,
                                                 const ushort* __restrict__ B,
                                                 float* __restrict__ C,
                                                 const float* __restrict__ bias) {
  const int K = 1024;
  __shared__ __align__(16) ushort As[2][2][128 * 32];  // [buf][k-half][row][32]
  __shared__ __align__(16) ushort Bs[2][2][64 * 32];
  const int m0 = blockIdx.y * 128, n0 = blockIdx.x * 64;
  const int tid = threadIdx.x, lane = tid & 63, wid = tid >> 6;
  const int quad = lane >> 4, lc = lane & 15;
  const int lrow = lane >> 2, lcol = (lane & 3) * 8;
  const int wm = (wid >> 1) * 64, wn = (wid & 1) * 32;

  f32x4 acc[4][2] = {};

  auto stage = [&](int k0, int nb) {
    const ushort* Ag = A + (size_t)(m0 + wid * 32 + lrow) * K + k0 + lcol;
    g2l16(Ag,                       &As[nb][0][wid * 1024]);
    g2l16(Ag + (size_t)16 * K,      &As[nb][0][wid * 1024 + 512]);
    g2l16(Ag + 32,                  &As[nb][1][wid * 1024]);
    g2l16(Ag + (size_t)16 * K + 32, &As[nb][1][wid * 1024 + 512]);
    const ushort* Bg = B + (size_t)(n0 + wid * 16 + lrow) * K + k0 + lcol;
    g2l16(Bg,      &Bs[nb][0][wid * 512]);
    g2l16(Bg + 32, &Bs[nb][1][wid * 512]);
  };

  stage(0, 0);
  for (int k0 = 0; k0 < K; k0 += 64) {
    const int nb = (k0 >> 6) & 1;
    __syncthreads();
    if (k0 + 64 < K) stage(k0 + 64, nb ^ 1);

#pragma unroll
    for (int ks = 0; ks < 2; ks++) {
      bf16x8 af[4], bfr[2];
#pragma unroll
      for (int t = 0; t < 4; t++)
        af[t] = *(const bf16x8*)&As[nb][ks][(wm + t * 16 + lc) * 32 + quad * 8];
#pragma unroll
      for (int t = 0; t < 2; t++)
        bfr[t] = *(const bf16x8*)&Bs[nb][ks][(wn + t * 16 + lc) * 32 + quad * 8];
#pragma unroll
      for (int mt = 0; mt < 4; mt++)
#pragma unroll
        for (int nt = 0; nt < 2; nt++)
          acc[mt][nt] = __builtin_amdgcn_mfma_f32_16x16x32_bf16(af[mt], bfr[nt], acc[mt][nt], 0, 0, 0);
    }
  }

#pragma unroll
  for (int mt = 0; mt < 4; mt++) {
#pragma unroll
    for (int r = 0; r < 4; r++) {
      int row = m0 + wm + mt * 16 + quad * 4 + r;
#pragma unroll
      for (int nt = 0; nt < 2; nt++) {
        int col = n0 + wn + nt * 16 + lc;
        C[(size_t)row * 1024 + col] = acc[mt][nt][r] + bias[col];
      }
    }
  }
}

// ---------------- V transpose: Vb[4096][1024] -> Vt[bh=32][d=64][t=2048]; zeroes L32 ----------------
__global__ __launch_bounds__(256) void transpose_v(const ushort* __restrict__ Vb,
                                                   ushort* __restrict__ Vt,
                                                   float4* __restrict__ L32z) {
  __shared__ ushort tile[64][72];
  const int bh = blockIdx.y, b = bh >> 4, h = bh & 15;
  const int tt = blockIdx.x;
  const int tid = threadIdx.x;
  if (bh == 0) {       // 32 blocks x 256 thr x 2 float4 = 65536 floats of L32
    int base = (tt * 256 + tid) * 2;
    L32z[base]     = float4{0.f, 0.f, 0.f, 0.f};
    L32z[base + 1] = float4{0.f, 0.f, 0.f, 0.f};
  }
#pragma unroll
  for (int i = 0; i < 2; i++) {
    int idx = i * 256 + tid;
    int trow = idx >> 3;
    int dcol = (idx & 7) * 8;
    uint4 v = *(const uint4*)(Vb + (size_t)(b * 2048 + tt * 64 + trow) * 1024 + h * 64 + dcol);
    ushort e[8]; *(uint4*)e = v;
#pragma unroll
    for (int j = 0; j < 8; j++) tile[dcol + j][trow] = e[j];
  }
  __syncthreads();
#pragma unroll
  for (int i = 0; i < 2; i++) {
    int idx = i * 256 + tid;
    int drow = idx >> 3;
    int tloc = (idx & 7) * 8;
    uint4 v = *(const uint4*)&tile[drow][tloc];
    *(uint4*)(Vt + (size_t)bh * 131072 + (size_t)drow * 2048 + tt * 64 + tloc) = v;
  }
}

// ---------------- chunked flash attention: 2 waves x 32q = 64q/block ----------------
// Grid (80, 32): blockIdx.y = bh; blockIdx.x -> (64-query block qi, key-chunk ci of <=8
// key-tiles of 64). Partials combine by addition (no-max softmax) via atomicAdd.
// l computed by MFMA with B=ones (no VALU adds, no shuffle reduction).
__global__ __launch_bounds__(128, 3) void attn_kernel(const ushort* __restrict__ Qb,
                                                      const ushort* __restrict__ Kb,
                                                      const ushort* __restrict__ Vt,
                                                      float* __restrict__ O32,
                                                      float* __restrict__ L32) {
  __shared__ __align__(16) ushort Ks[2][64 * 32];   // [d-half][key 64][d 32]
  __shared__ __align__(16) ushort Vs[2][64 * 32];   // [k-half][d 64][k 32]
  __shared__ __align__(16) ushort Ps[2][32][72];    // per-wave P tile [q 32][k 64+pad]

  const int bh = blockIdx.y, b = bh >> 4, h = bh & 15;
  // decode chunk id, heavy (8-tile) chunks first (round-4 proven)
  const int f = 79 - (int)blockIdx.x;
  int qi, ci;
  if (f < 8)       { qi = f;                 ci = 0; }
  else if (f < 24) { int g = f - 8;  qi = 8  + (g >> 1); ci = g & 1; }
  else if (f < 48) { int g = f - 24; int q3 = g / 3; qi = 16 + q3; ci = g - 3 * q3; }
  else             { int g = f - 48; qi = 24 + (g >> 2); ci = g & 3; }
  const int t0 = ci * 8;
  const int t1 = min(t0 + 8, qi + 1);

  const int tid = threadIdx.x, lane = tid & 63, wid = tid >> 6;   // wid in {0,1}
  const int quad = lane >> 4, lc = lane & 15;
  const int lrow = lane >> 2, lcol = (lane & 3) * 8;
  const int qbw = qi * 64 + wid * 32;

  const size_t kbase = (size_t)(b * 2048) * 1024 + h * 64;
  const size_t vbase = (size_t)bh * 131072;

  // Q fragments (A-layout), resident: 2 q-tiles x 2 k-halves
  bf16x8 qf[2][2];
#pragma unroll
  for (int t = 0; t < 2; t++) {
    const ushort* Qp = Qb + kbase + (size_t)(qbw + t * 16 + lc) * 1024;
    qf[t][0] = *(const bf16x8*)(Qp + quad * 8);
    qf[t][1] = *(const bf16x8*)(Qp + 32 + quad * 8);
  }

  bf16x8 ones;
#pragma unroll
  for (int j = 0; j < 8; j++) ones[j] = (short)0x3f80;   // bf16 1.0

  f32x4 o_acc[2][4] = {};
  f32x4 l_acc[2] = {};

  for (int kt = t0; kt < t1; kt++) {
    const int kb = kt * 64;
    __syncthreads();
    // wave wid stages d-half (K) / k-half (V) = wid, row-groups 0..3
#pragma unroll
    for (int j = 0; j < 4; j++) {
      const ushort* gK = Kb + kbase + (size_t)(kb + j * 16 + lrow) * 1024 + wid * 32 + lcol;
      g2l16(gK, &Ks[wid][j * 512]);
      const ushort* gV = Vt + vbase + (size_t)(j * 16 + lrow) * 2048 + kb + wid * 32 + lcol;
      g2l16(gV, &Vs[wid][j * 512]);
    }
    __syncthreads();

    // K fragments hoisted, shared across both q-tiles
    bf16x8 kf[4][2];
#pragma unroll
    for (int c = 0; c < 4; c++) {
      kf[c][0] = *(const bf16x8*)&Ks[0][(c * 16 + lc) * 32 + quad * 8];
      kf[c][1] = *(const bf16x8*)&Ks[1][(c * 16 + lc) * 32 + quad * 8];
    }

    // S = Q K^T (2 q-tiles x 64 keys), mask, exp2, scatter P
#pragma unroll
    for (int c = 0; c < 4; c++) {
#pragma unroll
      for (int t = 0; t < 2; t++) {
        f32x4 z = {};
        z = __builtin_amdgcn_mfma_f32_16x16x32_bf16(qf[t][0], kf[c][0], z, 0, 0, 0);
        z = __builtin_amdgcn_mfma_f32_16x16x32_bf16(qf[t][1], kf[c][1], z, 0, 0, 0);
        const bool diag = (kb + 63 > qbw + t * 16);   // wave-uniform
#pragma unroll
        for (int r = 0; r < 4; r++) {
          float sv = z[r];
          if (diag && (kb + c * 16 + lc > qbw + t * 16 + quad * 4 + r)) sv = -1e30f;
          Ps[wid][t * 16 + quad * 4 + r][c * 16 + lc] = f2bf(__builtin_amdgcn_exp2f(sv));
        }
      }
    }
    __asm__ volatile("s_waitcnt lgkmcnt(0)" ::: "memory");  // wave-local P ordering
    bf16x8 ap[2][2];
#pragma unroll
    for (int t = 0; t < 2; t++) {
      ap[t][0] = *(const bf16x8*)&Ps[wid][t * 16 + lc][quad * 8];
      ap[t][1] = *(const bf16x8*)&Ps[wid][t * 16 + lc][32 + quad * 8];
    }

    // l += P @ ones  (row sums via matrix pipe; replicated across lc)
#pragma unroll
    for (int t = 0; t < 2; t++) {
      l_acc[t] = __builtin_amdgcn_mfma_f32_16x16x32_bf16(ap[t][0], ones, l_acc[t], 0, 0, 0);
      l_acc[t] = __builtin_amdgcn_mfma_f32_16x16x32_bf16(ap[t][1], ones, l_acc[t], 0, 0, 0);
    }

    // O += P V (V fragments shared across both q-tiles)
#pragma unroll
    for (int nt = 0; nt < 4; nt++) {
      bf16x8 vb0 = *(const bf16x8*)&Vs[0][(nt * 16 + lc) * 32 + quad * 8];
      bf16x8 vb1 = *(const bf16x8*)&Vs[1][(nt * 16 + lc) * 32 + quad * 8];
#pragma unroll
      for (int t = 0; t < 2; t++) {
        o_acc[t][nt] = __builtin_amdgcn_mfma_f32_16x16x32_bf16(ap[t][0], vb0, o_acc[t][nt], 0, 0, 0);
        o_acc[t][nt] = __builtin_amdgcn_mfma_f32_16x16x32_bf16(ap[t][1], vb1, o_acc[t][nt], 0, 0, 0);
      }
    }
  }

  // partial (O, l) -> global accumulators
#pragma unroll
  for (int t = 0; t < 2; t++) {
    if (lc == 0) {
#pragma unroll
      for (int r = 0; r < 4; r++)
        atomicAdd(&L32[(size_t)bh * 2048 + qbw + t * 16 + quad * 4 + r], l_acc[t][r]);
    }
#pragma unroll
    for (int r = 0; r < 4; r++) {
      size_t orow = ((size_t)(b * 2048) + qbw + t * 16 + quad * 4 + r) * 1024 + h * 64 + lc;
#pragma unroll
      for (int nt = 0; nt < 4; nt++)
        atomicAdd(&O32[orow + nt * 16], o_acc[t][nt][r]);
    }
  }
}

// ---------------- normalize: O32/l -> bf16 attn_out ----------------
__global__ __launch_bounds__(256) void normalize_kernel(const float* __restrict__ O32,
                                                        const float* __restrict__ L32,
                                                        ushort* __restrict__ Out) {
  const int row = blockIdx.x;            // 0..4095  (b*2048 + t)
  const int tid = threadIdx.x;
  const int col = tid * 4;
  const int b = row >> 11, t = row & 2047, h = col >> 6;
  const float inv = 1.0f / L32[(size_t)(b * 16 + h) * 2048 + t];
  float4 o = ((const float4*)(O32 + (size_t)row * 1024))[tid];
  ushort4 u;
  u.x = f2bf(o.x * inv); u.y = f2bf(o.y * inv);
  u.z = f2bf(o.z * inv); u.w = f2bf(o.w * inv);
  ((ushort4*)(Out + (size_t)row * 1024))[tid] = u;
}

// ---------------- launcher ----------------
extern "C" void kernel_launch(void* const* d_in, const int* in_sizes, int n_in,
                              void* d_out, int out_size, void* d_ws, size_t ws_size,
                              hipStream_t stream) {
  const float* x  = (const float*)d_in[0];
  const float* Wq = (const float*)d_in[1];
  const float* Wk = (const float*)d_in[2];
  const float* Wv = (const float*)d_in[3];
  const float* Wo = (const float*)d_in[4];
  const float* bo = (const float*)d_in[5];
  float* out = (float*)d_out;

  char* ws = (char*)d_ws;
  ushort* xbf  = (ushort*)(ws);                  //  8 MB: x bf16 (dead after gemm_qkv)
  ushort* wcat = (ushort*)(ws + (8ull  << 20));  //  8 MB: Wcat bf16
  ushort* qkv  = (ushort*)(ws + (16ull << 20));  // 24 MB: Q | K | V planes
  ushort* Qp   = qkv;
  ushort* Kp   = qkv + (1ull << 22);
  ushort* Vp   = qkv + (2ull << 22);
  ushort* Vt   = (ushort*)(ws);                  //  8 MB: V^T over dead xbf
  float*  L32  = (float*)(ws + (12ull << 20));   // 256 KB over dead Wv rows of wcat
  float*  O32  = out;                            // d_out as fp32 accumulator scratch
  ushort* attn_out = Qp;                         // Q plane free after attn

  // cast x+weights, zero O32 (12288 blocks = 3M threads)
  cast_all<<<12288, 256, 0, stream>>>(x, Wq, Wk, Wv, Wo, xbf, wcat, (float4*)O32);

  // QKV = x @ Wcat[0:3072]^T -> 3 planes (Q pre-scaled by 0.125*log2e)
  gemm_qkv<<<dim3(24, 32), 256, 0, stream>>>(xbf, wcat, qkv);

  // V transpose + L32 zeroing (L32 region dead after gemm_qkv)
  transpose_v<<<dim3(32, 32), 256, 0, stream>>>(Vp, Vt, (float4*)L32);

  attn_kernel<<<dim3(80, 32), 128, 0, stream>>>(Qp, Kp, Vt, O32, L32);

  normalize_kernel<<<4096, 256, 0, stream>>>(O32, L32, attn_out);

  // out = attn_out @ Wo^T + bo   (overwrites O32 scratch, stream-ordered)
  gemm_proj<<<dim3(16, 32), 256, 0, stream>>>(
      attn_out, wcat + (size_t)3072 * 1024, out, bo);
}